// Round 5
// baseline (234.114 us; speedup 1.0000x reference)
//
#include <hip/hip_runtime.h>
#include <math.h>

#define NCLS 19
#define DIM  128
#define CD   (NCLS * DIM)   // 2432 floats
#define GPB  8              // 32-lane groups per 256-thread k_accum block

// Pass 1: per-class sums + counts. R5 restructure: per-32-lane-GROUP private
// LDS tables (8 x 9.5 KB = 76 KB -> 2 blocks/CU, 16 tables/CU as R4) and
// float4-per-lane rows so each WAVE load is 1 KiB contiguous (2 adjacent
// rows) instead of R4's 512 B. LDS RMW is one ds_read_b128/ds_write_b128
// pair per row on the group's own table - race-free, no atomics.
__global__ __launch_bounds__(256) void k_accum(const float4* __restrict__ in4,
                                               const int* __restrict__ tgt,
                                               float* __restrict__ gsums,
                                               int* __restrict__ gcounts,
                                               int n) {
    __shared__ __align__(16) float ls[GPB * CD];   // 77824 B
    __shared__ int lcnt[GPB * NCLS];
    const int tid = threadIdx.x;
    const int g   = tid >> 5;          // group 0..7
    const int l32 = tid & 31;
    float* tbl = &ls[g * CD];
    int*   cnt = &lcnt[g * NCLS];

    for (int i = tid; i < GPB * CD; i += 256) ls[i] = 0.0f;
    for (int i = tid; i < GPB * NCLS; i += 256) lcnt[i] = 0;
    __syncthreads();

    const int stride = gridDim.x * GPB;      // 512*8 = 4096 rows per step
    int row = blockIdx.x * GPB + g;

    for (; row + 3 * stride < n; row += 4 * stride) {
        // 4 rows in flight per group (4 KB per wave) before any LDS RMW
        float4 v0 = in4[(size_t)(row             ) * 32 + l32];
        float4 v1 = in4[(size_t)(row +     stride) * 32 + l32];
        float4 v2 = in4[(size_t)(row + 2 * stride) * 32 + l32];
        float4 v3 = in4[(size_t)(row + 3 * stride) * 32 + l32];
        int c0 = tgt[row];
        int c1 = tgt[row + stride];
        int c2 = tgt[row + 2 * stride];
        int c3 = tgt[row + 3 * stride];
        float4* p;
        float4 a;
        p = (float4*)&tbl[c0 * DIM + l32 * 4];
        a = *p; a.x += v0.x; a.y += v0.y; a.z += v0.z; a.w += v0.w; *p = a;
        p = (float4*)&tbl[c1 * DIM + l32 * 4];
        a = *p; a.x += v1.x; a.y += v1.y; a.z += v1.z; a.w += v1.w; *p = a;
        p = (float4*)&tbl[c2 * DIM + l32 * 4];
        a = *p; a.x += v2.x; a.y += v2.y; a.z += v2.z; a.w += v2.w; *p = a;
        p = (float4*)&tbl[c3 * DIM + l32 * 4];
        a = *p; a.x += v3.x; a.y += v3.y; a.z += v3.z; a.w += v3.w; *p = a;
        if (l32 == 0) { cnt[c0]++; cnt[c1]++; cnt[c2]++; cnt[c3]++; }
    }
    for (; row < n; row += stride) {
        float4 v = in4[(size_t)row * 32 + l32];
        int c = tgt[row];
        float4* p = (float4*)&tbl[c * DIM + l32 * 4];
        float4 a = *p;
        a.x += v.x; a.y += v.y; a.z += v.z; a.w += v.w;
        *p = a;
        if (l32 == 0) cnt[c]++;
    }
    __syncthreads();

    for (int i = tid; i < CD; i += 256) {
        float s = 0.0f;
        #pragma unroll
        for (int gg = 0; gg < GPB; gg++) s += ls[gg * CD + i];
        unsafeAtomicAdd(&gsums[i], s);
    }
    if (tid < NCLS) {
        int s = 0;
        #pragma unroll
        for (int gg = 0; gg < GPB; gg++) s += lcnt[gg * NCLS + tid];
        atomicAdd(&gcounts[tid], s);
    }
}

// Pass 2: distances. R5: unroll 4 rows per 32-lane group (4 KB/wave in
// flight). Centers staged in LDS; shuffle reduce; one native fadd per block.
__global__ __launch_bounds__(256) void k_dist(const float4* __restrict__ in4,
                                              const int* __restrict__ tgt,
                                              const float* __restrict__ gsums,
                                              const int* __restrict__ gcounts,
                                              float* __restrict__ out,
                                              int n, float inv_n) {
    __shared__ __align__(16) float lcent[CD];
    __shared__ float red[256];
    const int tid = threadIdx.x;

    for (int i = tid; i < CD; i += 256)
        lcent[i] = gsums[i] / (float)gcounts[i >> 7];
    __syncthreads();

    const int l32 = tid & 31;
    const int g   = tid >> 5;              // 0..7
    const int stride = gridDim.x * 8;      // 8192
    float acc = 0.0f;
    int row = blockIdx.x * 8 + g;

    for (; row + 3 * stride < n; row += 4 * stride) {
        float4 v0 = in4[(size_t)(row             ) * 32 + l32];
        float4 v1 = in4[(size_t)(row +     stride) * 32 + l32];
        float4 v2 = in4[(size_t)(row + 2 * stride) * 32 + l32];
        float4 v3 = in4[(size_t)(row + 3 * stride) * 32 + l32];
        int c0 = tgt[row];
        int c1 = tgt[row + stride];
        int c2 = tgt[row + 2 * stride];
        int c3 = tgt[row + 3 * stride];
        float4 e0 = *(const float4*)&lcent[c0 * DIM + l32 * 4];
        float4 e1 = *(const float4*)&lcent[c1 * DIM + l32 * 4];
        float4 e2 = *(const float4*)&lcent[c2 * DIM + l32 * 4];
        float4 e3 = *(const float4*)&lcent[c3 * DIM + l32 * 4];
        float dx, dy, dz, dw;
        dx = v0.x - e0.x; dy = v0.y - e0.y; dz = v0.z - e0.z; dw = v0.w - e0.w;
        float d0 = dx * dx + dy * dy + dz * dz + dw * dw;
        dx = v1.x - e1.x; dy = v1.y - e1.y; dz = v1.z - e1.z; dw = v1.w - e1.w;
        float d1 = dx * dx + dy * dy + dz * dz + dw * dw;
        dx = v2.x - e2.x; dy = v2.y - e2.y; dz = v2.z - e2.z; dw = v2.w - e2.w;
        float d2 = dx * dx + dy * dy + dz * dz + dw * dw;
        dx = v3.x - e3.x; dy = v3.y - e3.y; dz = v3.z - e3.z; dw = v3.w - e3.w;
        float d3 = dx * dx + dy * dy + dz * dz + dw * dw;
        for (int off = 16; off > 0; off >>= 1) {
            d0 += __shfl_down(d0, off, 32);
            d1 += __shfl_down(d1, off, 32);
            d2 += __shfl_down(d2, off, 32);
            d3 += __shfl_down(d3, off, 32);
        }
        if (l32 == 0) acc += sqrtf(d0) + sqrtf(d1) + sqrtf(d2) + sqrtf(d3);
    }
    for (; row < n; row += stride) {
        float4 v = in4[(size_t)row * 32 + l32];
        int c = tgt[row];
        float4 ce = *(const float4*)&lcent[c * DIM + l32 * 4];
        float dx = v.x - ce.x, dy = v.y - ce.y, dz = v.z - ce.z, dw = v.w - ce.w;
        float d2 = dx * dx + dy * dy + dz * dz + dw * dw;
        for (int off = 16; off > 0; off >>= 1)
            d2 += __shfl_down(d2, off, 32);
        if (l32 == 0) acc += sqrtf(d2);
    }

    red[tid] = acc;
    __syncthreads();
    for (int s = 128; s > 0; s >>= 1) {
        if (tid < s) red[tid] += red[tid + s];
        __syncthreads();
    }
    if (tid == 0) unsafeAtomicAdd(out, red[0] * inv_n);
}

extern "C" void kernel_launch(void* const* d_in, const int* in_sizes, int n_in,
                              void* d_out, int out_size, void* d_ws, size_t ws_size,
                              hipStream_t stream) {
    const float* in  = (const float*)d_in[0];
    const int*   tgt = (const int*)d_in[1];
    const int n = in_sizes[0] / DIM;

    float* gsums   = (float*)d_ws;             // [19][128]
    int*   gcounts = (int*)(gsums + CD);       // [19]
    float* out     = (float*)d_out;

    hipMemsetAsync(d_ws, 0, CD * sizeof(float) + NCLS * sizeof(int), stream);
    hipMemsetAsync(d_out, 0, sizeof(float), stream);

    k_accum<<<512, 256, 0, stream>>>((const float4*)in, tgt, gsums, gcounts, n);
    k_dist<<<1024, 256, 0, stream>>>((const float4*)in, tgt, gsums, gcounts, out,
                                     n, 1.0f / (float)n);
}